// Round 3
// baseline (405.778 us; speedup 1.0000x reference)
//
#include <hip/hip_runtime.h>
#include <hip/hip_bf16.h>

typedef _Float16 f16;
typedef _Float16 half8 __attribute__((ext_vector_type(8)));
typedef _Float16 half4 __attribute__((ext_vector_type(4)));
typedef float f32x4 __attribute__((ext_vector_type(4)));

typedef const __attribute__((address_space(1))) void gvoid;
typedef __attribute__((address_space(3))) void lvoid;
#define GLOAD16(src, dst) __builtin_amdgcn_global_load_lds((gvoid*)(src), (lvoid*)(dst), 16, 0, 0)

// ---------------- workspace layout (bytes) ----------------
#define WQV_OFF   0u          // f32 [256][256]  Wq*Vp
#define WKT_OFF   262144u     // f32 [256][256]  Wk*Tp
#define KP_OFF    524288u     // f32 [512][256]  fused k-projection (l*16+b rows)
#define W2S_OFF   1048576u    // f16 [16][256][256] per-batch score matrix
#define SBIAS_OFF 3145728u    // f32 [16][256]
#define BQV_OFF   3162112u    // f32 [256]
#define BKT_OFF   3163136u    // f32 [256]
#define W1H_OFF   3164160u    // f16 [256][256]
#define W2H_OFF   3295232u    // f16 [128][256]
#define VARP_OFF  3360768u    // f32 [16][256]
#define KTOP_OFF  3377152u    // i32 [16] (unused now)
#define SMM_OFF   3377280u    // u32 [16][2]
#define FMM_OFF   3377408u    // u32 [16][2]
#define CAND_OFF  3377664u    // f32 [9][16][16384]  plane-major candidates
#define FI_OFF    12814848u   // f32 [16][16384]
#define SIM_OFF   13863424u   // f32 [16][16384]

__device__ __forceinline__ float sigm(float x) { return 1.f / (1.f + __expf(-x)); }
__device__ __forceinline__ unsigned fmap(float f) {
  unsigned u = __float_as_uint(f);
  return (u & 0x80000000u) ? ~u : (u | 0x80000000u);
}
__device__ __forceinline__ float funmap(unsigned u) {
  unsigned b = (u & 0x80000000u) ? (u & 0x7FFFFFFFu) : ~u;
  return __uint_as_float(b);
}
__device__ __forceinline__ float rmax2(float x) {
  x = fmaxf(x, __shfl_xor(x, 16, 64));
  x = fmaxf(x, __shfl_xor(x, 32, 64));
  return x;
}
__device__ __forceinline__ float rsum2(float x) {
  x += __shfl_xor(x, 16, 64);
  x += __shfl_xor(x, 32, 64);
  return x;
}

// ---------------- P1: Wqv = Wq*Vp, Wkt = Wk*Tp, fused biases (+minmax init) --------
__global__ void k_p1(const float* __restrict__ ipw, const float* __restrict__ ipb,
                     const float* __restrict__ vp_w, const float* __restrict__ vp_b,
                     const float* __restrict__ tp_w, const float* __restrict__ tp_b,
                     float* __restrict__ Wqv, float* __restrict__ Wkt,
                     float* __restrict__ bqv, float* __restrict__ bkt,
                     unsigned* __restrict__ simMM, unsigned* __restrict__ fiMM) {
  int tx = threadIdx.x, ty = threadIdx.y;
  int bz = blockIdx.z;
  if (bz == 2) {
    if (blockIdx.x || blockIdx.y) return;
    if (ty == 0 && tx < 16) {
      simMM[tx * 2] = 0xFFFFFFFFu; simMM[tx * 2 + 1] = 0u;
      fiMM[tx * 2] = 0xFFFFFFFFu;  fiMM[tx * 2 + 1] = 0u;
    }
    int j = ty * 16 + tx;
    float s1 = 0.f, s2 = 0.f;
    for (int k = 0; k < 256; ++k) {
      s1 += ipw[j * 256 + k] * vp_b[k];
      s2 += ipw[65536 + j * 256 + k] * tp_b[k];
    }
    bqv[j] = s1 + ipb[j];
    bkt[j] = s2 + ipb[256 + j];
    return;
  }
  const float* A = ipw + (bz ? 65536 : 0);
  const float* B = bz ? tp_w : vp_w;
  float* O = bz ? Wkt : Wqv;
  __shared__ float As[16][16], Bs[16][17];
  int row = blockIdx.y * 16 + ty, col = blockIdx.x * 16 + tx;
  float s = 0.f;
  for (int tt = 0; tt < 16; ++tt) {
    As[ty][tx] = A[row * 256 + tt * 16 + tx];
    Bs[ty][tx] = B[(tt * 16 + ty) * 256 + col];
    __syncthreads();
#pragma unroll
    for (int k = 0; k < 16; ++k) s += As[ty][k] * Bs[k][tx];
    __syncthreads();
  }
  O[row * 256 + col] = s;
}

// ---------------- convert W1/W2 to f16 ----------------
__global__ void k_conv(const float* __restrict__ w1, const float* __restrict__ w2,
                       f16* __restrict__ W1h, f16* __restrict__ W2h) {
  int i = blockIdx.x * 256 + threadIdx.x;
  if (i < 65536) W1h[i] = (f16)w1[i];
  else if (i < 98304) W2h[i - 65536] = (f16)w2[i - 65536];
}

// ---------------- P2: kp[lb][i] = T[lb]·Wkt[i] + bkt[i] ----------------
__global__ void k_p2(const float* __restrict__ T, const float* __restrict__ Wkt,
                     const float* __restrict__ bkt, float* __restrict__ kp) {
  __shared__ float As[16][16], Ws[16][17];
  int tx = threadIdx.x, ty = threadIdx.y;
  int lb = blockIdx.y * 16 + ty;
  int i = blockIdx.x * 16 + tx;
  float s = 0.f;
  for (int tt = 0; tt < 16; ++tt) {
    As[ty][tx] = T[(size_t)lb * 256 + tt * 16 + tx];
    Ws[ty][tx] = Wkt[(size_t)(blockIdx.x * 16 + ty) * 256 + tt * 16 + tx];
    __syncthreads();
#pragma unroll
    for (int k = 0; k < 16; ++k) s += As[ty][k] * Ws[tx][k];
    __syncthreads();
  }
  kp[(size_t)lb * 256 + i] = s + bkt[i];
}

// ---------------- P3: W2s[b][h*32+l][c], sbias ----------------
__global__ void k_p3(const float* __restrict__ kp, const float* __restrict__ Wqv,
                     const float* __restrict__ bqv, f16* __restrict__ W2s,
                     float* __restrict__ sbias) {
  const float SC = 0.17677669529663687f; // 1/sqrt(32)
  int b = blockIdx.z, jt = blockIdx.y, ct = blockIdx.x;
  int ty = threadIdx.y, tx = threadIdx.x;
  int j2 = jt * 16 + ty, c = ct * 16 + tx;
  int h = j2 >> 5, l = j2 & 31;
  const float* kr = kp + (size_t)(l * 16 + b) * 256 + h * 32;
  const float* wq = Wqv + (size_t)h * 32 * 256 + c;
  float s = 0.f;
#pragma unroll
  for (int d = 0; d < 32; ++d) s += kr[d] * wq[(size_t)d * 256];
  W2s[(size_t)b * 65536 + j2 * 256 + c] = (f16)(s * SC);
  if (ct == 0 && tx == 0) {
    float sb = 0.f;
#pragma unroll
    for (int d = 0; d < 32; ++d) sb += kr[d] * bqv[h * 32 + d];
    sbias[b * 256 + j2] = sb * SC;
  }
}

// ============ FUSED: scores GEMM (swapped) + softmax + top16  |  MLP (2xGEMM+LN) ============
// block: 512 thr (8 waves); tile = 64 rows (n at batch b) x full K=256.
// LDS: [0,32K)=X f16[64][256] swz (later vpart f32[4][64][32] xor), [32K,96K)=B dbuf
//      (parity 32K: {W2s-tile 16K, W1-tile 16K} / mlp2: W2-tile 16K), [96K,128K)=h1
__global__ void __launch_bounds__(512, 2) k_fused(
    const float* __restrict__ X, const f16* __restrict__ W2s,
    const float* __restrict__ sbias,
    const f16* __restrict__ W1h, const float* __restrict__ b1,
    const float* __restrict__ g1, const float* __restrict__ be1,
    const f16* __restrict__ W2h, const float* __restrict__ b2,
    const float* __restrict__ g2, const float* __restrict__ be2,
    const float* __restrict__ w3, const float* __restrict__ b3,
    float* __restrict__ cand, float* __restrict__ varpart, float* __restrict__ fi) {
  __shared__ __align__(16) char smem[131072];
  __shared__ float pS[64][2], pQ[64][2];
  const int b = blockIdx.y;
  const int bx = blockIdx.x;
  const int n0 = bx * 64;
  const int t = threadIdx.x;
  const int w = t >> 6;
  const int lane = t & 63;
  const int ln = lane & 15, kg = lane >> 4;
  const int jg = w >> 1;   // scores: j-range 64 ; mlp: n-frag
  const int ng = w & 1;    // scores: n-range 32 ; mlp: out-half

  char* Albs = smem;
  char* Bbs = smem + 32768;
  char* H1 = smem + 98304;

  const int ar = t >> 3, aq = t & 7;
  const float* Xrow = X + (((size_t)(n0 + ar)) * 16 + b) * 256;
  const unsigned asw = (unsigned)((ar & 7) << 4);
  const char* W2sb = (const char*)(W2s + (size_t)b * 65536);
  const char* W1b = (const char*)W1h;
  const char* W2b = (const char*)W2h;

  f32x4 acc[4][2];   // scores: [j-frag][n-frag]
  f32x4 acc1[8];     // mlp1:  [out-frag]
#pragma unroll
  for (int mj = 0; mj < 4; ++mj)
#pragma unroll
    for (int nn = 0; nn < 2; ++nn)
#pragma unroll
      for (int i = 0; i < 4; ++i) acc[mj][nn][i] = 0.f;
#pragma unroll
  for (int no = 0; no < 8; ++no)
#pragma unroll
    for (int i = 0; i < 4; ++i) acc1[no][i] = 0.f;

  auto issue_sc = [&](int kt, int p) {
#pragma unroll
    for (int i = 0; i < 2; ++i) {
      int g = i * 512 + t;
      int j = g >> 2, c16 = g & 3;
      GLOAD16(W2sb + (size_t)j * 512 + kt * 64 + (c16 << 4),
              Bbs + p * 32768 + ((i * 8 + w) << 10));
      GLOAD16(W1b + (size_t)j * 512 + kt * 64 + (c16 << 4),
              Bbs + p * 32768 + 16384 + ((i * 8 + w) << 10));
    }
  };
  auto issue_m2 = [&](int kt, int p) {
#pragma unroll
    for (int i = 0; i < 2; ++i) {
      int g = i * 512 + t;
      int j = g >> 3, c16 = g & 7;
      GLOAD16(W2b + (size_t)j * 512 + kt * 128 + (((unsigned)c16 ^ (unsigned)(j & 7)) << 4),
              Bbs + p * 32768 + ((i * 8 + w) << 10));
    }
  };
  auto loadx = [&](int kt) -> f32x4 { return *(const f32x4*)(Xrow + kt * 32 + aq * 4); };
  auto storex = [&](int kt, f32x4 v) {
    half4 hv;
    hv[0] = (f16)v[0]; hv[1] = (f16)v[1]; hv[2] = (f16)v[2]; hv[3] = (f16)v[3];
    *(half4*)(Albs + ((unsigned)(ar * 512 + kt * 64 + aq * 8) ^ asw)) = hv;
  };
  auto mfma_sc = [&](int kt, int p) {
    char* bp = Bbs + p * 32768;
    {
      half8 av[4], bv[2];
#pragma unroll
      for (int mj = 0; mj < 4; ++mj)
        av[mj] = *(const half8*)(bp + (jg * 64 + mj * 16 + ln) * 64 + kg * 16);
#pragma unroll
      for (int nn = 0; nn < 2; ++nn) {
        int R = ng * 32 + nn * 16 + ln;
        bv[nn] = *(const half8*)(Albs + ((unsigned)(R * 512 + kt * 64 + kg * 16) ^ ((unsigned)(R & 7) << 4)));
      }
#pragma unroll
      for (int mj = 0; mj < 4; ++mj)
#pragma unroll
        for (int nn = 0; nn < 2; ++nn)
          acc[mj][nn] = __builtin_amdgcn_mfma_f32_16x16x32_f16(av[mj], bv[nn], acc[mj][nn], 0, 0, 0);
    }
    {
      half8 aw, bw[8];
      int R = jg * 16 + ln;
      aw = *(const half8*)(Albs + ((unsigned)(R * 512 + kt * 64 + kg * 16) ^ ((unsigned)(R & 7) << 4)));
#pragma unroll
      for (int no = 0; no < 8; ++no)
        bw[no] = *(const half8*)(bp + 16384 + (ng * 128 + no * 16 + ln) * 64 + kg * 16);
#pragma unroll
      for (int no = 0; no < 8; ++no)
        acc1[no] = __builtin_amdgcn_mfma_f32_16x16x32_f16(aw, bw[no], acc1[no], 0, 0, 0);
    }
  };

  // ---- prologue ----
  issue_sc(0, 0);
  f32x4 xq0 = loadx(0);
  f32x4 xq1 = loadx(1);
  storex(0, xq0);
  __syncthreads();

  // ---- interleaved scores + MLP1 over 8 K-chunks of 32 ----
#pragma unroll
  for (int kt = 0; kt < 8; ++kt) {
    if (kt < 7) issue_sc(kt + 1, (kt + 1) & 1);
    else issue_m2(0, 0);
    if (kt < 6) {
      if (((kt + 2) & 1) == 0) xq0 = loadx(kt + 2);
      else xq1 = loadx(kt + 2);
    }
    if (kt < 7) {
      if (((kt + 1) & 1) == 0) storex(kt + 1, xq0);
      else storex(kt + 1, xq1);
    }
    mfma_sc(kt, kt & 1);
    __syncthreads();
  }

  // ---- scores epilogue: per-head softmax in-register (D[j][n] layout) ----
  // j = jg*64 + mj*16 + kg*4 + r ; n = ng*32 + nn*16 + ln
  {
    float sbv[4][4];
#pragma unroll
    for (int mj = 0; mj < 4; ++mj)
      *(f32x4*)sbv[mj] = *(const f32x4*)(sbias + b * 256 + jg * 64 + mj * 16 + kg * 4);
    float vm[2][2][4];
#pragma unroll
    for (int lh = 0; lh < 2; ++lh)
#pragma unroll
      for (int nn = 0; nn < 2; ++nn)
#pragma unroll
        for (int r = 0; r < 4; ++r) vm[lh][nn][r] = 0.f;
#pragma unroll
    for (int hh = 0; hh < 2; ++hh)
#pragma unroll
      for (int nn = 0; nn < 2; ++nn) {
        float v8[2][4];
        float mx = -1e30f;
#pragma unroll
        for (int lh = 0; lh < 2; ++lh)
#pragma unroll
          for (int r = 0; r < 4; ++r) {
            v8[lh][r] = acc[hh * 2 + lh][nn][r] + sbv[hh * 2 + lh][r];
            mx = fmaxf(mx, v8[lh][r]);
          }
        mx = rmax2(mx);
        float S = 0.f;
#pragma unroll
        for (int lh = 0; lh < 2; ++lh)
#pragma unroll
          for (int r = 0; r < 4; ++r) { v8[lh][r] = __expf(v8[lh][r] - mx); S += v8[lh][r]; }
        S = rsum2(S);
        float inv = 0.125f / S;
#pragma unroll
        for (int lh = 0; lh < 2; ++lh)
#pragma unroll
          for (int r = 0; r < 4; ++r) vm[lh][nn][r] += v8[lh][r] * inv;
      }
    // write partial head-means into (dead) X region, xor-swizzled cols
    float* vp = (float*)Albs;
#pragma unroll
    for (int lh = 0; lh < 2; ++lh)
#pragma unroll
      for (int nn = 0; nn < 2; ++nn)
#pragma unroll
        for (int r = 0; r < 4; ++r) {
          int n = ng * 32 + nn * 16 + ln;
          int l = lh * 16 + kg * 4 + r;
          vp[(jg * 64 + n) * 32 + (l ^ ((n & 7) << 2))] = vm[lh][nn][r];
        }
  }

  // ---- MLP1 LN part 1 (row sums) ----
  float b1v[8], g1v[8], e1v[8];
#pragma unroll
  for (int no = 0; no < 8; ++no) {
    int J = ng * 128 + no * 16 + ln;
    b1v[no] = b1[J]; g1v[no] = g1[J]; e1v[no] = be1[J];
  }
#pragma unroll
  for (int no = 0; no < 8; ++no)
#pragma unroll
    for (int r = 0; r < 4; ++r) acc1[no][r] += b1v[no];
#pragma unroll
  for (int r = 0; r < 4; ++r) {
    float s = 0.f, q = 0.f;
#pragma unroll
    for (int no = 0; no < 8; ++no) { float x = acc1[no][r]; s += x; q += x * x; }
#pragma unroll
    for (int m = 1; m < 16; m <<= 1) { s += __shfl_xor(s, m, 64); q += __shfl_xor(q, m, 64); }
    if (ln == 0) { int R = jg * 16 + kg * 4 + r; pS[R][ng] = s; pQ[R][ng] = q; }
  }
  __syncthreads();  // vpart visible, pS/pQ visible, mlp2-kt0 drained

  // ---- MLP1 LN part 2 -> h1 ----
#pragma unroll
  for (int r = 0; r < 4; ++r) {
    int R = jg * 16 + kg * 4 + r;
    float mean = (pS[R][0] + pS[R][1]) * (1.f / 256.f);
    float var = (pQ[R][0] + pQ[R][1]) * (1.f / 256.f) - mean * mean;
    float rstd = rsqrtf(var + 1e-5f);
#pragma unroll
    for (int no = 0; no < 8; ++no) {
      int J = ng * 128 + no * 16 + ln;
      float y = (acc1[no][r] - mean) * rstd * g1v[no] + e1v[no];
      y = fmaxf(y, 0.f);
      *(f16*)(H1 + ((unsigned)(R * 512 + J * 2) ^ ((unsigned)(R & 7) << 4))) = (f16)y;
    }
  }

  // ---- wave0: head-mean merge, variance, top-16, candidates ----
  if (t < 64) {
    const float* vp = (const float*)Albs;
    float v[32];
    unsigned csw = (unsigned)((t & 7) << 2);
#pragma unroll
    for (int l = 0; l < 32; ++l) {
      unsigned ls = (unsigned)l ^ csw;
      v[l] = vp[(0 * 64 + t) * 32 + ls] + vp[(1 * 64 + t) * 32 + ls] +
             vp[(2 * 64 + t) * 32 + ls] + vp[(3 * 64 + t) * 32 + ls];
    }
    float s2 = 0.f;
#pragma unroll
    for (int l = 0; l < 32; ++l) s2 += v[l] * v[l];
    float vr = (s2 - (1.f / 32.f)) * (1.f / 31.f);
#pragma unroll
    for (int m = 1; m < 64; m <<= 1) vr += __shfl_xor(vr, m, 64);
    if (t == 0) varpart[b * 256 + bx] = vr;
    // bitonic sort descending
#pragma unroll
    for (int k = 2; k <= 32; k <<= 1) {
#pragma unroll
      for (int j = k >> 1; j > 0; j >>= 1) {
#pragma unroll
        for (int i = 0; i < 32; ++i) {
          int l = i ^ j;
          if (l > i) {
            float a = v[i], c = v[l];
            float hi = fmaxf(a, c), lo = fminf(a, c);
            bool up = ((i & k) == 0);
            v[i] = up ? hi : lo;
            v[l] = up ? lo : hi;
          }
        }
      }
    }
    float m0 = v[0], se = 0.f, te = 0.f;
    float cn[9];
#pragma unroll
    for (int i = 0; i < 16; ++i) {
      float e = __expf(v[i] - m0);
      se += e; te += v[i] * e;
      if (i >= 7) cn[i - 7] = te / se;
    }
#pragma unroll
    for (int i = 0; i < 9; ++i)
      cand[(size_t)i * 262144 + (size_t)b * 16384 + n0 + t] = cn[i];
  }
  __syncthreads();  // h1 visible

  // ---- MLP2: h2 = h1 @ W2^T over 4 K-chunks of 64 ----
  f32x4 acc2[4];
#pragma unroll
  for (int no = 0; no < 4; ++no)
#pragma unroll
    for (int i = 0; i < 4; ++i) acc2[no][i] = 0.f;
#pragma unroll
  for (int kt = 0; kt < 4; ++kt) {
    if (kt < 3) issue_m2(kt + 1, (kt + 1) & 1);
    char* bp = Bbs + (kt & 1) * 32768;
#pragma unroll
    for (int ks = 0; ks < 2; ++ks) {
      half8 av, bv[4];
      int R = jg * 16 + ln;
      av = *(const half8*)(H1 + ((unsigned)(R * 512 + kt * 128 + ks * 64 + kg * 16) ^ ((unsigned)(R & 7) << 4)));
#pragma unroll
      for (int no = 0; no < 4; ++no) {
        int J = ng * 64 + no * 16 + ln;
        bv[no] = *(const half8*)(bp + ((unsigned)(J * 128 + ks * 64 + kg * 16) ^ ((unsigned)(J & 7) << 4)));
      }
#pragma unroll
      for (int no = 0; no < 4; ++no)
        acc2[no] = __builtin_amdgcn_mfma_f32_16x16x32_f16(av, bv[no], acc2[no], 0, 0, 0);
    }
    if (kt < 3) __syncthreads();
  }

  // ---- LN2 + ReLU + w3 dot + sigmoid -> fi ----
  float b2v[4], g2v[4], e2v[4], w3v[4];
#pragma unroll
  for (int no = 0; no < 4; ++no) {
    int J = ng * 64 + no * 16 + ln;
    b2v[no] = b2[J]; g2v[no] = g2[J]; e2v[no] = be2[J]; w3v[no] = w3[J];
  }
#pragma unroll
  for (int no = 0; no < 4; ++no)
#pragma unroll
    for (int r = 0; r < 4; ++r) acc2[no][r] += b2v[no];
  __syncthreads();  // all prior pS/pQ reads done before reuse
#pragma unroll
  for (int r = 0; r < 4; ++r) {
    float s = 0.f, q = 0.f;
#pragma unroll
    for (int no = 0; no < 4; ++no) { float x = acc2[no][r]; s += x; q += x * x; }
#pragma unroll
    for (int m = 1; m < 16; m <<= 1) { s += __shfl_xor(s, m, 64); q += __shfl_xor(q, m, 64); }
    if (ln == 0) { int R = jg * 16 + kg * 4 + r; pS[R][ng] = s; pQ[R][ng] = q; }
  }
  __syncthreads();
  float a3p[4];
#pragma unroll
  for (int r = 0; r < 4; ++r) {
    int R = jg * 16 + kg * 4 + r;
    float mean = (pS[R][0] + pS[R][1]) * (1.f / 128.f);
    float var = (pQ[R][0] + pQ[R][1]) * (1.f / 128.f) - mean * mean;
    float rstd = rsqrtf(var + 1e-5f);
    float a3 = 0.f;
#pragma unroll
    for (int no = 0; no < 4; ++no) {
      float y = (acc2[no][r] - mean) * rstd * g2v[no] + e2v[no];
      y = fmaxf(y, 0.f);
      a3 += y * w3v[no];
    }
#pragma unroll
    for (int m = 1; m < 16; m <<= 1) a3 += __shfl_xor(a3, m, 64);
    a3p[r] = a3;
  }
  __syncthreads();
  if (ln == 0) {
#pragma unroll
    for (int r = 0; r < 4; ++r) { int R = jg * 16 + kg * 4 + r; pS[R][ng] = a3p[r]; }
  }
  __syncthreads();
  if (ng == 0 && ln == 0) {
    float b3v = b3[0];
#pragma unroll
    for (int r = 0; r < 4; ++r) {
      int R = jg * 16 + kg * 4 + r;
      fi[(size_t)b * 16384 + n0 + R] = sigm(pS[R][0] + pS[R][1] + b3v);
    }
  }
}

// ---------------- G4: ktop + pick sim candidate + min/max reductions ----------------
__global__ void __launch_bounds__(256) k_g4(
    const float* __restrict__ cand, const float* __restrict__ fi,
    const float* __restrict__ varpart, const float* __restrict__ kw,
    float* __restrict__ sim, unsigned* __restrict__ simMM, unsigned* __restrict__ fiMM) {
  __shared__ float red[4][4];
  __shared__ int kS;
  int b = blockIdx.x >> 6;
  if (threadIdx.x < 64) {
    float s = 0.f;
#pragma unroll
    for (int i = 0; i < 4; ++i) s += varpart[b * 256 + threadIdx.x + i * 64];
#pragma unroll
    for (int m = 1; m < 64; m <<= 1) s += __shfl_xor(s, m, 64);
    if (threadIdx.x == 0) {
      float var = s * (1.f / 16384.f);
      float kws = sigm(kw[0]);
      float ratio = fminf(fmaxf(kws * (1.f + var * 0.5f), 0.25f), 0.6f);
      int kb = (int)floorf(32.f * ratio);
      if (kb < 1) kb = 1;
      int kt = kb < 16 ? kb : 16;
      if (kt < 8) kt = 8;
      kS = kt;
    }
  }
  __syncthreads();
  int k = kS;
  int n = (blockIdx.x & 63) * 256 + threadIdx.x;
  size_t idx = (size_t)b * 16384 + n;
  float sv = cand[(size_t)(k - 8) * 262144 + idx];
  sim[idx] = sv;
  float fv = fi[idx];
  float sn = sv, sx = sv, fn = fv, fx = fv;
#pragma unroll
  for (int m = 1; m < 64; m <<= 1) {
    sn = fminf(sn, __shfl_xor(sn, m, 64));
    sx = fmaxf(sx, __shfl_xor(sx, m, 64));
    fn = fminf(fn, __shfl_xor(fn, m, 64));
    fx = fmaxf(fx, __shfl_xor(fx, m, 64));
  }
  int wv = threadIdx.x >> 6;
  if ((threadIdx.x & 63) == 0) { red[0][wv] = sn; red[1][wv] = sx; red[2][wv] = fn; red[3][wv] = fx; }
  __syncthreads();
  if (threadIdx.x == 0) {
    float a = red[0][0], c = red[1][0], d = red[2][0], e = red[3][0];
#pragma unroll
    for (int i = 1; i < 4; ++i) {
      a = fminf(a, red[0][i]); c = fmaxf(c, red[1][i]);
      d = fminf(d, red[2][i]); e = fmaxf(e, red[3][i]);
    }
    atomicMin(&simMM[b * 2 + 0], fmap(a));
    atomicMax(&simMM[b * 2 + 1], fmap(c));
    atomicMin(&fiMM[b * 2 + 0], fmap(d));
    atomicMax(&fiMM[b * 2 + 1], fmap(e));
  }
}

// ---------------- G5: normalize, combine, transpose-write ----------------
__global__ void __launch_bounds__(256) k_g5(
    const float* __restrict__ sim, const float* __restrict__ fi,
    const unsigned* __restrict__ simMM, const unsigned* __restrict__ fiMM,
    const float* __restrict__ ac, const float* __restrict__ af,
    float* __restrict__ out) {
  __shared__ float ls[256][17], lf[256][17];
  __shared__ float sMin[16], sInv[16], fMin[16], fInv[16];
  int t = threadIdx.x;
  int n0 = blockIdx.x * 256;
  if (t < 16) {
    float lo = funmap(simMM[t * 2]), hi = funmap(simMM[t * 2 + 1]);
    float r = hi - lo;
    sMin[t] = lo; sInv[t] = (r > 0.f) ? 1.f / r : 0.f;
    lo = funmap(fiMM[t * 2]); hi = funmap(fiMM[t * 2 + 1]);
    r = hi - lo;
    fMin[t] = lo; fInv[t] = (r > 0.f) ? 1.f / r : 0.f;
  }
#pragma unroll
  for (int i = 0; i < 16; ++i) {
    ls[t][i] = sim[(size_t)i * 16384 + n0 + t];
    lf[t][i] = fi[(size_t)i * 16384 + n0 + t];
  }
  __syncthreads();
  float alpha = 0.5f * (sigm(ac[0]) + sigm(af[0]));
  float o[16];
#pragma unroll
  for (int b = 0; b < 16; ++b) {
    float s = (ls[t][b] - sMin[b]) * sInv[b];
    float f = (lf[t][b] - fMin[b]) * fInv[b];
    o[b] = alpha * s + (1.f - alpha) * f;
  }
  float* op = out + (size_t)(n0 + t) * 16;
#pragma unroll
  for (int i = 0; i < 4; ++i) {
    f32x4 v;
    v[0] = o[i * 4]; v[1] = o[i * 4 + 1]; v[2] = o[i * 4 + 2]; v[3] = o[i * 4 + 3];
    *(f32x4*)(op + i * 4) = v;
  }
}

// ---------------- launcher ----------------
extern "C" void kernel_launch(void* const* d_in, const int* in_sizes, int n_in,
                              void* d_out, int out_size, void* d_ws, size_t ws_size,
                              hipStream_t stream) {
  const float* X    = (const float*)d_in[0];
  const float* T    = (const float*)d_in[1];
  const float* vp_w = (const float*)d_in[2];
  const float* vp_b = (const float*)d_in[3];
  const float* tp_w = (const float*)d_in[4];
  const float* tp_b = (const float*)d_in[5];
  const float* ipw  = (const float*)d_in[6];
  const float* ipb  = (const float*)d_in[7];
  const float* w1   = (const float*)d_in[8];
  const float* b1   = (const float*)d_in[9];
  const float* g1   = (const float*)d_in[10];
  const float* be1  = (const float*)d_in[11];
  const float* w2   = (const float*)d_in[12];
  const float* b2   = (const float*)d_in[13];
  const float* g2   = (const float*)d_in[14];
  const float* be2  = (const float*)d_in[15];
  const float* w3   = (const float*)d_in[16];
  const float* b3   = (const float*)d_in[17];
  const float* kw   = (const float*)d_in[18];
  const float* ac   = (const float*)d_in[19];
  const float* af   = (const float*)d_in[20];
  char* ws = (char*)d_ws;
  float* Wqv = (float*)(ws + WQV_OFF);
  float* Wkt = (float*)(ws + WKT_OFF);
  float* kp = (float*)(ws + KP_OFF);
  f16* W2s = (f16*)(ws + W2S_OFF);
  float* sbias = (float*)(ws + SBIAS_OFF);
  float* bqv = (float*)(ws + BQV_OFF);
  float* bkt = (float*)(ws + BKT_OFF);
  f16* W1h = (f16*)(ws + W1H_OFF);
  f16* W2h = (f16*)(ws + W2H_OFF);
  float* varpart = (float*)(ws + VARP_OFF);
  unsigned* simMM = (unsigned*)(ws + SMM_OFF);
  unsigned* fiMM = (unsigned*)(ws + FMM_OFF);
  float* cand = (float*)(ws + CAND_OFF);
  float* fi = (float*)(ws + FI_OFF);
  float* sim = (float*)(ws + SIM_OFF);
  float* out = (float*)d_out;

  k_p1<<<dim3(16, 16, 3), dim3(16, 16), 0, stream>>>(ipw, ipb, vp_w, vp_b, tp_w, tp_b,
                                                     Wqv, Wkt, bqv, bkt, simMM, fiMM);
  k_conv<<<384, 256, 0, stream>>>(w1, w2, W1h, W2h);
  k_p2<<<dim3(16, 32), dim3(16, 16), 0, stream>>>(T, Wkt, bkt, kp);
  k_p3<<<dim3(16, 16, 16), dim3(16, 16), 0, stream>>>(kp, Wqv, bqv, W2s, sbias);
  k_fused<<<dim3(256, 16), 512, 0, stream>>>(X, W2s, sbias, W1h, b1, g1, be1,
                                             W2h, b2, g2, be2, w3, b3, cand, varpart, fi);
  k_g4<<<1024, 256, 0, stream>>>(cand, fi, varpart, kw, sim, simMM, fiMM);
  k_g5<<<64, 256, 0, stream>>>(sim, fi, simMM, fiMM, ac, af, out);
}